// Round 6
// baseline (38.730 us; speedup 1.0000x reference)
//
#include <hip/hip_runtime.h>

#define DEVFN __device__ __forceinline__

typedef float f32x4 __attribute__((ext_vector_type(4)));

DEVFN float min3f(float a, float b, float c) { return fminf(fminf(a, b), c); }
DEVFN float max3f(float a, float b, float c) { return fmaxf(fmaxf(a, b), c); }
DEVFN float med3f(float a, float b, float c) {
    return fmaxf(fminf(a, b), fminf(fmaxf(a, b), c));
}

// Fixed shape: 16 x 3 x 512 x 512 f32, 3x3 median with zero padding,
// plus pass-through copy of `cover` into out+n.
//
// One WAVE owns a full 512-wide x 4-row output band: lane i covers pixels
// [8i, 8i+8). Horizontal halos come from __shfl of the neighboring lane's
// edge registers (lane 0 / 63 halos ARE the zero padding) -> zero scalar
// halo loads; every VMEM instruction is a fully coalesced 1 KB wave op.
// Per-thread VMEM: 12 row loads + 8 cover loads + 16 stores over 32 px
// (vs 30 per 16 px before). XCD-chunked block swizzle for halo L2 reuse.
__global__ __launch_bounds__(256) void median3x3_wave(
        const float* __restrict__ in, const float* __restrict__ cover,
        float* __restrict__ out, float* __restrict__ out2, int chunk) {
    constexpr int W = 512;
    constexpr int H = 512;

    int bid = blockIdx.x;
    int swz = (bid & 7) * chunk + (bid >> 3);      // bijective: grid % 8 == 0
    int gtid = swz * blockDim.x + threadIdx.x;
    int band = gtid >> 6;                          // one band per wave
    int lane = threadIdx.x & 63;

    int plane = band >> 7;                         // 128 bands per plane
    int y0    = (band & 127) << 2;                 // first output row
    int x0    = lane << 3;

    long rbase = ((long)plane << 18) + ((long)y0 << 9) + x0;
    const float* rowp = in + rbase;

    // rows y0-1 .. y0+4 ; a = px[0..3], b = px[4..7] of this lane's 8-px slab
    f32x4 a[6], b[6];
    #pragma unroll
    for (int t = 0; t < 4; ++t) {
        const float* rp = rowp + (t << 9);
        a[t + 1] = *reinterpret_cast<const f32x4*>(rp);
        b[t + 1] = *reinterpret_cast<const f32x4*>(rp + 4);
    }
    if (y0 > 0) {
        a[0] = *reinterpret_cast<const f32x4*>(rowp - W);
        b[0] = *reinterpret_cast<const f32x4*>(rowp - W + 4);
    } else {
        a[0] = (f32x4)0.0f; b[0] = (f32x4)0.0f;
    }
    if (y0 + 4 < H) {
        a[5] = *reinterpret_cast<const f32x4*>(rowp + (4 << 9));
        b[5] = *reinterpret_cast<const f32x4*>(rowp + (4 << 9) + 4);
    } else {
        a[5] = (f32x4)0.0f; b[5] = (f32x4)0.0f;
    }

    // cover pass-through loads (independent; issue early for MLP)
    f32x4 ca[4], cb[4];
    #pragma unroll
    for (int t = 0; t < 4; ++t) {
        const float* cp = cover + rbase + (t << 9);
        ca[t] = *reinterpret_cast<const f32x4*>(cp);
        cb[t] = *reinterpret_cast<const f32x4*>(cp + 4);
    }

    // 10 columns per row: [halo_l, a.xyzw, b.xyzw, halo_r]
    float col[6][10];
    #pragma unroll
    for (int r = 0; r < 6; ++r) {
        float hl = __shfl_up(b[r].w, 1);           // lane i-1's px 8i-1
        float hr = __shfl_down(a[r].x, 1);         // lane i+1's px 8i+8
        if (lane == 0)  hl = 0.0f;                 // x = -1  -> zero pad
        if (lane == 63) hr = 0.0f;                 // x = 512 -> zero pad
        col[r][0] = hl;
        col[r][1] = a[r].x; col[r][2] = a[r].y; col[r][3] = a[r].z; col[r][4] = a[r].w;
        col[r][5] = b[r].x; col[r][6] = b[r].y; col[r][7] = b[r].z; col[r][8] = b[r].w;
        col[r][9] = hr;
    }

    #pragma unroll
    for (int t = 0; t < 4; ++t) {
        float cmn[10], cmd[10], cmx[10];
        #pragma unroll
        for (int j = 0; j < 10; ++j) {
            float p = col[t][j], q = col[t + 1][j], s = col[t + 2][j];
            cmn[j] = min3f(p, q, s);
            cmx[j] = max3f(p, q, s);
            cmd[j] = med3f(p, q, s);
        }
        f32x4 oa, ob;
        #pragma unroll
        for (int i = 0; i < 8; ++i) {
            float lo = max3f(cmn[i], cmn[i + 1], cmn[i + 2]);
            float hi = min3f(cmx[i], cmx[i + 1], cmx[i + 2]);
            float mi = med3f(cmd[i], cmd[i + 1], cmd[i + 2]);
            float r  = med3f(lo, mi, hi);
            if (i < 4) oa[i] = r; else ob[i - 4] = r;
        }
        float* op = out + rbase + (t << 9);
        *reinterpret_cast<f32x4*>(op)     = oa;
        *reinterpret_cast<f32x4*>(op + 4) = ob;
        float* o2 = out2 + rbase + (t << 9);
        *reinterpret_cast<f32x4*>(o2)     = ca[t];
        *reinterpret_cast<f32x4*>(o2 + 4) = cb[t];
    }
}

extern "C" void kernel_launch(void* const* d_in, const int* in_sizes, int n_in,
                              void* d_out, int out_size, void* d_ws, size_t ws_size,
                              hipStream_t stream) {
    const float* noised = (const float*)d_in[0];
    const float* cover  = (const float*)d_in[1];
    float* out = (float*)d_out;

    const int n = in_sizes[0];                 // 16*3*512*512 = 12582912
    const int rows_total = n / 512;            // 24576
    const int bands = rows_total / 4;          // 6144 (one wave each)
    const int block = 256;                     // 4 waves per block
    const int grid = bands / 4;                // 1536 (divisible by 8)
    const int chunk = grid / 8;                // 192

    median3x3_wave<<<grid, block, 0, stream>>>(noised, cover, out, out + n, chunk);
}

// Round 7
// 34.847 us; speedup vs baseline: 1.1114x; 1.1114x over previous
//
#include <hip/hip_runtime.h>

#define DEVFN __device__ __forceinline__

typedef float f32x4 __attribute__((ext_vector_type(4)));

DEVFN float min3f(float a, float b, float c) { return fminf(fminf(a, b), c); }
DEVFN float max3f(float a, float b, float c) { return fmaxf(fmaxf(a, b), c); }
DEVFN float med3f(float a, float b, float c) {
    return fmaxf(fminf(a, b), fminf(fmaxf(a, b), c));
}

// Fixed shape: 16 x 3 x 512 x 512 f32, 3x3 median with zero padding,
// plus pass-through copy of `cover` into out+n.
// Body identical to the round-4 best (4x4 tile/thread, wave-contiguous
// f32x4 loads, scalar L1-hit halos, XCD-chunked swizzle, nt stores).
// ONLY change: 64-thread blocks (1 wave) -> grid 12288. With 36 VGPR a CU
// holds 32 waves; fine-grained blocks let the scheduler drain wave-by-wave
// instead of in 4-wave chunks (grid was 12 blocks/CU = rounds of 8 then 4,
// second round half-empty -> measured 52% occupancy).
__global__ __launch_bounds__(64) void median3x3_w64(
        const float* __restrict__ in, const float* __restrict__ cover,
        float* __restrict__ out, float* __restrict__ out2, int chunk) {
    constexpr int W = 512;
    constexpr int H = 512;

    // bijective chunked XCD swizzle (grid % 8 == 0)
    int bid = blockIdx.x;
    int swz = (bid & 7) * chunk + (bid >> 3);
    int tid = swz * 64 + threadIdx.x;

    int rg  = tid >> 7;                 // row-band id, 4 rows each
    int g   = tid & 127;                // horizontal group
    int x0  = g << 2;
    int plane = rg >> 7;                // 128 row-bands per 512-row plane
    int y0  = (rg & 127) << 2;          // first output row in plane

    int rbase = (plane << 18) + (y0 << 9) + x0;   // element index of (y0, x0)
    const float* rowp = in + rbase;

    // v[0] = row y0-1 (halo), v[1..4] = rows y0..y0+3, v[5] = row y0+4 (halo)
    float v[6][6];

    #pragma unroll
    for (int t = 0; t < 4; ++t) {
        const float* rp = rowp + (t << 9);
        f32x4 c = *reinterpret_cast<const f32x4*>(rp);
        v[t + 1][1] = c.x; v[t + 1][2] = c.y; v[t + 1][3] = c.z; v[t + 1][4] = c.w;
        v[t + 1][0] = (x0 > 0)     ? rp[-1] : 0.0f;
        v[t + 1][5] = (x0 + 4 < W) ? rp[4]  : 0.0f;
    }
    if (y0 > 0) {
        const float* rp = rowp - W;
        f32x4 c = *reinterpret_cast<const f32x4*>(rp);
        v[0][1] = c.x; v[0][2] = c.y; v[0][3] = c.z; v[0][4] = c.w;
        v[0][0] = (x0 > 0)     ? rp[-1] : 0.0f;
        v[0][5] = (x0 + 4 < W) ? rp[4]  : 0.0f;
    } else {
        #pragma unroll
        for (int j = 0; j < 6; ++j) v[0][j] = 0.0f;
    }
    if (y0 + 4 < H) {
        const float* rp = rowp + (4 << 9);
        f32x4 c = *reinterpret_cast<const f32x4*>(rp);
        v[5][1] = c.x; v[5][2] = c.y; v[5][3] = c.z; v[5][4] = c.w;
        v[5][0] = (x0 > 0)     ? rp[-1] : 0.0f;
        v[5][5] = (x0 + 4 < W) ? rp[4]  : 0.0f;
    } else {
        #pragma unroll
        for (int j = 0; j < 6; ++j) v[5][j] = 0.0f;
    }

    // cover pass-through (independent loads, overlap with median compute)
    f32x4 cv[4];
    #pragma unroll
    for (int t = 0; t < 4; ++t)
        cv[t] = *reinterpret_cast<const f32x4*>(cover + rbase + (t << 9));

    #pragma unroll
    for (int t = 0; t < 4; ++t) {
        float cmn[6], cmd[6], cmx[6];
        #pragma unroll
        for (int j = 0; j < 6; ++j) {
            float a = v[t][j], b = v[t + 1][j], c = v[t + 2][j];
            cmn[j] = min3f(a, b, c);
            cmx[j] = max3f(a, b, c);
            cmd[j] = med3f(a, b, c);
        }
        f32x4 o;
        #pragma unroll
        for (int i = 0; i < 4; ++i) {
            float lo = max3f(cmn[i], cmn[i + 1], cmn[i + 2]);
            float hi = min3f(cmx[i], cmx[i + 1], cmx[i + 2]);
            float mi = med3f(cmd[i], cmd[i + 1], cmd[i + 2]);
            o[i] = med3f(lo, mi, hi);
        }
        __builtin_nontemporal_store(o,     reinterpret_cast<f32x4*>(out  + rbase + (t << 9)));
        __builtin_nontemporal_store(cv[t], reinterpret_cast<f32x4*>(out2 + rbase + (t << 9)));
    }
}

extern "C" void kernel_launch(void* const* d_in, const int* in_sizes, int n_in,
                              void* d_out, int out_size, void* d_ws, size_t ws_size,
                              hipStream_t stream) {
    const float* noised = (const float*)d_in[0];
    const float* cover  = (const float*)d_in[1];
    float* out = (float*)d_out;

    const int n = in_sizes[0];                  // 16*3*512*512 = 12582912
    const int rows_total = n / 512;             // 24576
    const int row_groups = rows_total / 4;      // 6144
    const int threads_total = row_groups * 128; // 786432
    const int block = 64;
    const int grid = threads_total / block;     // 12288 (divisible by 8)
    const int chunk = grid / 8;                 // 1536

    median3x3_w64<<<grid, block, 0, stream>>>(noised, cover, out, out + n, chunk);
}